// Round 9
// baseline (158.792 us; speedup 1.0000x reference)
//
#include <hip/hip_runtime.h>
#include <math.h>

// Problem geometry (fixed by setup_inputs)
#define NN 2
#define DD 160
#define HH 192
#define WW 160
#define DO 154   // DD-6
#define HO 186   // HH-6
#define WO 154   // WW-6

#define NWO 3    // wo tiles of 64
#define HOT 8    // ho tile
#define NHO 24   // ceil(186/8)
#define ZCH 7    // z chunks: 154 = 7*22 exactly -> every block nslice=28=2*14
#define ZOC 22
#define NSL 28   // ZOC+6, compile-time constant for ALL blocks
#define NB (NWO * NHO * NN * ZCH)   // 1008 blocks = 1.97 generations at 2/CU

// LDS-only barrier: s_waitcnt lgkmcnt(0) (vmcnt left outstanding) + s_barrier.
#define LDS_SYNC() do { __builtin_amdgcn_s_waitcnt(0xC07F); __builtin_amdgcn_s_barrier(); } while (0)

__device__ __forceinline__ float block_sum(float v, float* sm) {
  int tid = threadIdx.x;
  sm[tid] = v;
  __syncthreads();
#pragma unroll
  for (int off = 128; off > 0; off >>= 1) {
    if (tid < off) sm[tid] += sm[tid + off];
    __syncthreads();
  }
  float r = sm[0];
  __syncthreads();
  return r;
}

__device__ __forceinline__ float block_min(float v, float* sm) {
  int tid = threadIdx.x;
  sm[tid] = v;
  __syncthreads();
#pragma unroll
  for (int off = 128; off > 0; off >>= 1) {
    if (tid < off) sm[tid] = fminf(sm[tid], sm[tid + off]);
    __syncthreads();
  }
  float r = sm[0];
  __syncthreads();
  return r;
}

__device__ __forceinline__ float wave_sum(float v) {
  v += __shfl_xor(v, 32); v += __shfl_xor(v, 16); v += __shfl_xor(v, 8);
  v += __shfl_xor(v, 4);  v += __shfl_xor(v, 2);  v += __shfl_xor(v, 1);
  return v;
}

__device__ __forceinline__ float wave_min(float v) {
  v = fminf(v, __shfl_xor(v, 32)); v = fminf(v, __shfl_xor(v, 16));
  v = fminf(v, __shfl_xor(v, 8));  v = fminf(v, __shfl_xor(v, 4));
  v = fminf(v, __shfl_xor(v, 2));  v = fminf(v, __shfl_xor(v, 1));
  return v;
}

// 7-tap sliding W-sum over 10 inputs -> 4 outputs into R buffer RB.
// W4 at row stride 64: bank-quad residues get exactly 8 lanes each -> 0 conflicts (r3).
#define SLIDE7(RB, V, M) do { \
  float s0 = ((V[0]+V[1])+(V[2]+V[3])) + ((V[4]+V[5])+V[6]); \
  float s1 = s0 - V[0] + V[7]; \
  float s2 = s1 - V[1] + V[8]; \
  float s3 = s2 - V[2] + V[9]; \
  *(float4*)&R[RB][M][rA][c4] = make_float4(s0, s1, s2, s3); \
} while (0)

#define LOADA(SIN) do { if (okA) { \
  const float* xp = XrowA + (size_t)(z0 + (SIN)) * slice; \
  const float* yp = YrowA + (size_t)(z0 + (SIN)) * slice; \
  lx0 = *(const float4*)xp;       lx1 = *(const float4*)(xp + 4); \
  ly0 = *(const float4*)yp;       ly1 = *(const float4*)(yp + 4); \
  if (!tail) { lx2 = *(const float2*)(xp + 8); ly2 = *(const float2*)(yp + 8); } \
  else       { lx2 = make_float2(0.f, 0.f);    ly2 = make_float2(0.f, 0.f); } \
} } while (0)

#define STOREA(RB) do { if (okA) { \
  const float x[10] = {lx0.x,lx0.y,lx0.z,lx0.w, lx1.x,lx1.y,lx1.z,lx1.w, lx2.x,lx2.y}; \
  const float y[10] = {ly0.x,ly0.y,ly0.z,ly0.w, ly1.x,ly1.y,ly1.z,ly1.w, ly2.x,ly2.y}; \
  SLIDE7(RB, x, 0); \
  SLIDE7(RB, y, 1); \
  { float t[10]; \
    _Pragma("unroll") for (int i = 0; i < 10; ++i) t[i] = x[i] * x[i]; \
    SLIDE7(RB, t, 2); } \
  { float t[10]; \
    _Pragma("unroll") for (int i = 0; i < 10; ++i) t[i] = y[i] * y[i]; \
    SLIDE7(RB, t, 3); } \
  { float t[10]; \
    _Pragma("unroll") for (int i = 0; i < 10; ++i) t[i] = x[i] * y[i]; \
    SLIDE7(RB, t, 4); } \
} } while (0)

// Phase O from Mh buffer MB with static ring index U (0..6).
#define PHASEO(U, S, MB) do { \
  float ma0 = Mh[MB][0][ty][tx], mb0 = Mh[MB][0][ty+4][tx]; \
  float ma1 = Mh[MB][1][ty][tx], mb1 = Mh[MB][1][ty+4][tx]; \
  float ma2 = Mh[MB][2][ty][tx], mb2 = Mh[MB][2][ty+4][tx]; \
  float ma3 = Mh[MB][3][ty][tx], mb3 = Mh[MB][3][ty+4][tx]; \
  float ma4 = Mh[MB][4][ty][tx], mb4 = Mh[MB][4][ty+4][tx]; \
  zs0[0] += ma0 - h0[0][U]; h0[0][U] = ma0;  zs0[1] += mb0 - h0[1][U]; h0[1][U] = mb0; \
  zs1[0] += ma1 - h1[0][U]; h1[0][U] = ma1;  zs1[1] += mb1 - h1[1][U]; h1[1][U] = mb1; \
  zs2[0] += ma2 - h2[0][U]; h2[0][U] = ma2;  zs2[1] += mb2 - h2[1][U]; h2[1][U] = mb2; \
  zs3[0] += ma3 - h3[0][U]; h3[0][U] = ma3;  zs3[1] += mb3 - h3[1][U]; h3[1][U] = mb3; \
  zs4[0] += ma4 - h4[0][U]; h4[0][U] = ma4;  zs4[1] += mb4 - h4[1][U]; h4[1][U] = mb4; \
  if ((S) >= 6) { \
    if (act0) { \
      float num = zs4[0] - zs0[0] * zs1[0] * inv_nw; \
      float d0  = zs2[0] - zs0[0] * zs0[0] * inv_nw; \
      float d1  = zs3[0] - zs1[0] * zs1[0] * inv_nw; \
      float den = d0 * d1; \
      if (den > 1e-5f) { \
        float ncc = num * __frsqrt_rn(den); \
        if (ncc >= LO && ncc <= HI) { \
          float v = 0.5f * (d0 + d1); \
          p_snv += ncc * v; p_sn += ncc; p_sv += v; p_cnt += 1.f; \
          p_vmin = fminf(p_vmin, v); \
        } } } \
    if (act1) { \
      float num = zs4[1] - zs0[1] * zs1[1] * inv_nw; \
      float d0  = zs2[1] - zs0[1] * zs0[1] * inv_nw; \
      float d1  = zs3[1] - zs1[1] * zs1[1] * inv_nw; \
      float den = d0 * d1; \
      if (den > 1e-5f) { \
        float ncc = num * __frsqrt_rn(den); \
        if (ncc >= LO && ncc <= HI) { \
          float v = 0.5f * (d0 + d1); \
          p_snv += ncc * v; p_sn += ncc; p_sv += v; p_cnt += 1.f; \
          p_vmin = fminf(p_vmin, v); \
        } } } \
  } \
} while (0)

// One pipeline step, SINGLE barrier. K literal 0..13; B = K&1 (buffers for
// slice s); BN = 1-B; U = K%7 (base is a multiple of 14 -> U == s%7).
// Hazards (all cross-wave pairs separated by exactly one barrier):
//   H(s) reads R[B]   <- storeA(s) wrote it before barrier(s-1)
//   storeA(s+1)->R[BN]: last reader H(s-1) was before barrier(s-1)
//   H(s) writes Mh[B]: last reader O(s-2) was before barrier(s-1)
//   O(s) reads Mh[B]  <- written by H(s) before barrier(s)
//   O(s) runs beside H(s+1): different Mh buffers
// Loads never span a barrier: issued after barrier(s), consumed by
// storeA(s+2) before barrier(s+1) -> one load reg set, register-neutral vs r3.
#define STEP(K, B, BN, U) do { \
  const int s = base + (K); \
  phaseH(B); \
  if (s + 1 < NSL) STOREA(BN);          /* vmcnt wait lands here */ \
  LDS_SYNC();                            /* the only barrier */ \
  if (s + 2 < NSL) LOADA(s + 2);         /* shadow = phaseO + next phaseH */ \
  PHASEO(U, s, B); \
} while (0)

// (256,3): do NOT tighten to (256,4) — 128-reg cap spills the Z-history ring
// (round-2: 31 MB writeback). Measured budget at (256,3): ~170 unified regs;
// r3 steady state ~150 -> NO new architectural state (round-7: +24 regs -> spill).
__global__ __launch_bounds__(256, 3) void ncc_fused(const float* __restrict__ X,
                                                    const float* __restrict__ Y,
                                                    float* __restrict__ part) {
  __shared__ __align__(16) float R[2][5][14][64];   // 35.8 KB double-buffered W moments
  __shared__ __align__(16) float Mh[2][5][HOT][64]; // 20.5 KB double-buffered W+H moments
  __shared__ float red[4][5];                       // 56.4 KB total < 64 KB/WG cap

  const int tid = threadIdx.x;
  const int tx = tid & 63, ty = tid >> 6;
  const int wo0 = blockIdx.x * 64;
  const int ho0 = blockIdx.y * HOT;
  const int n   = blockIdx.z / ZCH;
  const int ck  = blockIdx.z % ZCH;
  const int z0  = ck * ZOC;

  const int wo = wo0 + tx;
  const bool act0 = (wo < WO) && (ho0 + ty < HO);
  const bool act1 = (wo < WO) && (ho0 + ty + 4 < HO);

  const size_t slice = (size_t)HH * WW;
  const float* Xn = X + (size_t)n * DD * slice;
  const float* Yn = Y + (size_t)n * DD * slice;
  const float inv_nw = 1.0f / 343.0f;
  const float LO = -1.0f - 1e-5f, HI = 1.0f + 1e-5f;

  // Phase-A item: 224 items; item p -> row rA=p>>4 (0..13), 4 outputs at cols c4..c4+3.
  const int pA  = tid;
  const bool hasA = (pA < 224);
  const int rA  = pA >> 4;
  const int c4  = (pA & 15) << 2;
  const int hA  = ho0 + rA;
  const int baseW = wo0 + c4;                  // multiple of 4
  const bool okA  = hasA && (hA < HH) && (baseW < WO);
  const bool tail = okA && (baseW + 10 > WW);  // only baseW==152: read 8, zero 2
  const float* XrowA = Xn + (size_t)hA * WW + baseW;
  const float* YrowA = Yn + (size_t)hA * WW + baseW;

  float4 lx0={0,0,0,0}, lx1={0,0,0,0};
  float4 ly0={0,0,0,0}, ly1={0,0,0,0};
  float2 lx2={0,0}, ly2={0,0};

  // Phase H: 7-tap sliding H-sums, 14 rows -> 8 outputs per (ch, w).
  // ch=ty for all waves; wave 3 also does ch4 (its phase-A is half-masked).
  auto phaseHitem = [&](int b, int ch, int w) {
    const float* rp = &R[b][ch][0][w];
    float r0=rp[0],   r1=rp[64],  r2=rp[128], r3=rp[192], r4=rp[256],
          r5=rp[320], r6=rp[384], r7=rp[448], r8=rp[512], r9=rp[576],
          r10=rp[640], r11=rp[704], r12=rp[768], r13=rp[832];
    float m0 = ((r0+r1)+(r2+r3)) + ((r4+r5)+r6);
    float m1 = m0 - r0 + r7;
    float m2 = m1 - r1 + r8;
    float m3 = m2 - r2 + r9;
    float m4 = m3 - r3 + r10;
    float m5 = m4 - r4 + r11;
    float m6 = m5 - r5 + r12;
    float m7 = m6 - r6 + r13;
    Mh[b][ch][0][w]=m0; Mh[b][ch][1][w]=m1; Mh[b][ch][2][w]=m2; Mh[b][ch][3][w]=m3;
    Mh[b][ch][4][w]=m4; Mh[b][ch][5][w]=m5; Mh[b][ch][6][w]=m6; Mh[b][ch][7][w]=m7;
  };
  auto phaseH = [&](int b) {
    phaseHitem(b, ty, tx);
    if (ty == 3) phaseHitem(b, 4, tx);
  };

  // Sliding-window Z accumulation: zs += m_new - hist[u]; hist[u] = m_new.
  // Ring index U is a macro literal -> stays in registers/AGPRs.
  float zs0[2]={0,0}, zs1[2]={0,0}, zs2[2]={0,0}, zs3[2]={0,0}, zs4[2]={0,0};
  float h0[2][7], h1[2][7], h2[2][7], h3[2][7], h4[2][7];
#pragma unroll
  for (int j = 0; j < 7; ++j) {
    h0[0][j]=0.f; h1[0][j]=0.f; h2[0][j]=0.f; h3[0][j]=0.f; h4[0][j]=0.f;
    h0[1][j]=0.f; h1[1][j]=0.f; h2[1][j]=0.f; h3[1][j]=0.f; h4[1][j]=0.f;
  }
  float p_snv = 0.f, p_sn = 0.f, p_sv = 0.f, p_cnt = 0.f, p_vmin = 3.4e38f;

  // Prologue: slice 0 staged to R[0]; slice 1 loads in flight.
  LOADA(0);
  STOREA(0);
  __syncthreads();
  LOADA(1);

#pragma unroll 1
  for (int base = 0; base < NSL; base += 14) {   // NSL = 28 = 2*14; base%14==0
    STEP(0,  0, 1, 0);
    STEP(1,  1, 0, 1);
    STEP(2,  0, 1, 2);
    STEP(3,  1, 0, 3);
    STEP(4,  0, 1, 4);
    STEP(5,  1, 0, 5);
    STEP(6,  0, 1, 6);
    STEP(7,  1, 0, 0);
    STEP(8,  0, 1, 1);
    STEP(9,  1, 0, 2);
    STEP(10, 0, 1, 3);
    STEP(11, 1, 0, 4);
    STEP(12, 0, 1, 5);
    STEP(13, 1, 0, 6);
  }

  // Wave-level reduction (6 shfl each), then 4 partials through LDS.
  float r0 = wave_sum(p_snv);
  float r1 = wave_sum(p_sn);
  float r2 = wave_sum(p_sv);
  float r3 = wave_sum(p_cnt);
  float r4 = wave_min(p_vmin);
  if (tx == 0) {
    red[ty][0]=r0; red[ty][1]=r1; red[ty][2]=r2; red[ty][3]=r3; red[ty][4]=r4;
  }
  __syncthreads();
  if (tid == 0) {
    float s0 = (red[0][0]+red[1][0]) + (red[2][0]+red[3][0]);
    float s1 = (red[0][1]+red[1][1]) + (red[2][1]+red[3][1]);
    float s2 = (red[0][2]+red[1][2]) + (red[2][2]+red[3][2]);
    float s3 = (red[0][3]+red[1][3]) + (red[2][3]+red[3][3]);
    float s4 = fminf(fminf(red[0][4],red[1][4]), fminf(red[2][4],red[3][4]));
    const int bid = blockIdx.x + NWO * (blockIdx.y + NHO * blockIdx.z);
    float* pp = part + (size_t)bid * 8;
    pp[0] = s0; pp[1] = s1; pp[2] = s2; pp[3] = s3; pp[4] = s4;
  }
}

// Reduce NB per-block partials; loss = 1 - (S_nv - vmin*S_n)/(S_v - vmin*cnt)
// (the min-max weight scale HIGH/(vmax-vmin+1e-12) cancels in w/sum(w)).
__global__ __launch_bounds__(256) void fin(const float* __restrict__ part,
                                           float* __restrict__ out) {
  __shared__ float sm[256];
  const int tid = threadIdx.x;
  float s0 = 0.f, s1 = 0.f, s2 = 0.f, s3 = 0.f, vm = 3.4e38f;
  for (int b = tid; b < NB; b += 256) {
    const float* pp = part + (size_t)b * 8;
    s0 += pp[0]; s1 += pp[1]; s2 += pp[2]; s3 += pp[3];
    vm = fminf(vm, pp[4]);
  }
  s0 = block_sum(s0, sm);
  s1 = block_sum(s1, sm);
  s2 = block_sum(s2, sm);
  s3 = block_sum(s3, sm);
  vm = block_min(vm, sm);
  if (tid == 0) {
    out[0] = 1.0f - (s0 - vm * s1) / (s2 - vm * s3);
  }
}

extern "C" void kernel_launch(void* const* d_in, const int* in_sizes, int n_in,
                              void* d_out, int out_size, void* d_ws, size_t ws_size,
                              hipStream_t stream) {
  const float* X = (const float*)d_in[0];  // y_pred
  const float* Y = (const float*)d_in[1];  // y_true
  // d_in[2]: ones kernel, constant, unused.

  float* part = (float*)d_ws;  // NB * 8 floats = 31.5 KB

  dim3 g(NWO, NHO, NN * ZCH);
  ncc_fused<<<g, 256, 0, stream>>>(X, Y, part);
  fin<<<1, 256, 0, stream>>>(part, (float*)d_out);
}